// Round 4
// baseline (444.860 us; speedup 1.0000x reference)
//
#include <hip/hip_runtime.h>
#include <hip/hip_bf16.h>
#include <stdint.h>

// frames: (B=4,S=8,N=2,C=4,H=480,W=640) f32 -> dense (32, 8ch, 480, 640)
// mask = max_c |dense[bf,c,y,x]| > 3.0 ; emit first 200000 survivors in
// (bf,y,x) row-major order. out = [features 200000x8][coords 200000x4].
#define HW        307200        // 480*640
#define W_IMG     640
#define TILE      1024          // pixels per block (256 thr x float4)
#define NTILES    9600          // 32*307200/1024
#define BLK_PER_BF 300          // HW/TILE (tiles never straddle a bf image)
#define MAXPTS    200000
#define COORD_OFF 1600000       // 200000*8 floats

// ws layout (SoA):
//   [0)         u32 counts[NTILES]                     38,400 B
//   [65536)     u32 offsets[NTILES]                    38,400 B
//   [131072)    u32 pixid[NTILES*TILE]             39,321,600 B
//   [39452672)  f32 feats[NTILES*TILE][8]         314,572,800 B
#define WS_OFFSETS 65536
#define WS_PIXID   131072
#define WS_FEATS   39452672

__device__ __forceinline__ float comp4(const float4& q, int i) {
    return i == 0 ? q.x : i == 1 ? q.y : i == 2 ? q.z : q.w;
}

__global__ __launch_bounds__(256) void compact_kernel(
        const float* __restrict__ frames, unsigned* __restrict__ counts,
        unsigned* __restrict__ pixid, float* __restrict__ feats) {
    __shared__ unsigned s_wsum[4];

    int tid  = threadIdx.x;
    int lane = tid & 63, wave = tid >> 6;
    int tile = blockIdx.x;

    int bf      = tile / BLK_PER_BF;
    int pixBase = (tile - bf * BLK_PER_BF) * TILE + tid * 4;
    const float* base = frames + (size_t)bf * (8 * (size_t)HW) + pixBase;

    // 8 channels x float4 (4 consecutive pixels) = 128 B/thread, coalesced
    float4 v[8];
#pragma unroll
    for (int c = 0; c < 8; ++c)
        v[c] = *(const float4*)(base + (size_t)c * HW);

    float m0 = 0.f, m1 = 0.f, m2 = 0.f, m3 = 0.f;
#pragma unroll
    for (int c = 0; c < 8; ++c) {
        m0 = fmaxf(m0, fabsf(v[c].x));
        m1 = fmaxf(m1, fabsf(v[c].y));
        m2 = fmaxf(m2, fabsf(v[c].z));
        m3 = fmaxf(m3, fabsf(v[c].w));
    }
    int k0 = m0 > 3.0f, k1 = m1 > 3.0f, k2 = m2 > 3.0f, k3 = m3 > 3.0f;
    unsigned cnt = (unsigned)(k0 + k1 + k2 + k3);

    // wave-inclusive scan of per-thread counts (thread order == pixel order)
    unsigned inc = cnt;
#pragma unroll
    for (int off = 1; off < 64; off <<= 1) {
        unsigned n = __shfl_up(inc, off, 64);
        if (lane >= off) inc += n;
    }
    if (lane == 63) s_wsum[wave] = inc;
    __syncthreads();
    unsigned wbase = 0;
#pragma unroll
    for (int w = 0; w < 4; ++w)
        if (w < wave) wbase += s_wsum[w];
    unsigned excl = wbase + inc - cnt;    // block-local exclusive prefix

    if (tid == 255) counts[tile] = excl + cnt;   // block total

    // write survivors compacted within this tile's slot
    unsigned slot = (unsigned)tile * TILE + excl;
    int k[4] = {k0, k1, k2, k3};
#pragma unroll
    for (int i = 0; i < 4; ++i) {
        if (k[i]) {
            float4* p = (float4*)(feats + (size_t)slot * 8);
            p[0] = make_float4(comp4(v[0], i), comp4(v[1], i),
                               comp4(v[2], i), comp4(v[3], i));
            p[1] = make_float4(comp4(v[4], i), comp4(v[5], i),
                               comp4(v[6], i), comp4(v[7], i));
            pixid[slot] = (unsigned)bf * HW + (unsigned)(pixBase + i);
            slot++;
        }
    }
}

__global__ __launch_bounds__(256) void scan_kernel(const unsigned* __restrict__ counts,
                                                   unsigned* __restrict__ offsets) {
    __shared__ unsigned s_w[4];
    int tid  = threadIdx.x;
    int lane = tid & 63, wave = tid >> 6;
    const int per = (NTILES + 255) / 256;  // 38
    int begin = tid * per;
    int end   = begin + per > NTILES ? NTILES : begin + per;
    unsigned sum = 0;
    unsigned c[per];
    for (int i = begin; i < end; ++i) { c[i - begin] = counts[i]; sum += c[i - begin]; }

    // wave-inclusive scan of per-thread sums
    unsigned inc = sum;
#pragma unroll
    for (int off = 1; off < 64; off <<= 1) {
        unsigned n = __shfl_up(inc, off, 64);
        if (lane >= off) inc += n;
    }
    if (lane == 63) s_w[wave] = inc;
    __syncthreads();
    unsigned wbase = 0;
#pragma unroll
    for (int w = 0; w < 4; ++w)
        if (w < wave) wbase += s_w[w];
    unsigned acc = wbase + inc - sum;      // exclusive prefix of this thread's range
    for (int i = begin; i < end; ++i) { offsets[i] = acc; acc += c[i - begin]; }
}

__global__ __launch_bounds__(256) void scatter_kernel(
        const float* __restrict__ feats, const unsigned* __restrict__ pixid,
        const unsigned* __restrict__ counts, const unsigned* __restrict__ offsets,
        float* __restrict__ out) {
    int tile = blockIdx.x;
    unsigned g = offsets[tile];
    unsigned c = counts[tile];
    for (unsigned j = threadIdx.x; j < c; j += 256) {
        unsigned r = g + j;
        if (r >= MAXPTS) break;
        unsigned slot = (unsigned)tile * TILE + j;
        const float4* p = (const float4*)(feats + (size_t)slot * 8);
        float4 f0 = p[0], f1 = p[1];
        unsigned pid = pixid[slot];
        unsigned bf  = pid / HW;
        unsigned pix = pid - bf * HW;
        unsigned y   = pix / W_IMG;
        unsigned x   = pix - y * W_IMG;
        float4* fo = (float4*)(out + (size_t)r * 8);
        fo[0] = f0;
        fo[1] = f1;
        ((float4*)(out + COORD_OFF))[r] =
            make_float4((float)(bf >> 3), (float)(bf & 7), (float)y, (float)x);
    }
}

extern "C" void kernel_launch(void* const* d_in, const int* in_sizes, int n_in,
                              void* d_out, int out_size, void* d_ws, size_t ws_size,
                              hipStream_t stream) {
    const float* frames = (const float*)d_in[0];
    float* out = (float*)d_out;

    char* ws = (char*)d_ws;
    unsigned* counts  = (unsigned*)ws;
    unsigned* offsets = (unsigned*)(ws + WS_OFFSETS);
    unsigned* pixid   = (unsigned*)(ws + WS_PIXID);
    float*    feats   = (float*)(ws + WS_FEATS);

    // rows >= n_valid must read 0 (harness poisons d_out each call)
    hipMemsetAsync(d_out, 0, (size_t)out_size * sizeof(float), stream);

    compact_kernel<<<NTILES, 256, 0, stream>>>(frames, counts, pixid, feats);
    scan_kernel<<<1, 256, 0, stream>>>(counts, offsets);
    scatter_kernel<<<NTILES, 256, 0, stream>>>(feats, pixid, counts, offsets, out);
}